// Round 5
// baseline (228.217 us; speedup 1.0000x reference)
//
#include <hip/hip_runtime.h>
#include <hip/hip_bf16.h>
#include <math.h>

#define B_  32
#define T_  128
#define NF_ 20
#define D_  512
#define S_  5
#define L_  96
#define EPS_ 1e-8f
#define NSEG (B_ * L_)                       // 3072
#define NPOS (NF_ - 1)                       // 19
#define NELEM (NF_ * D_)                     // 10240 floats = 40 KB
#define RPAD (D_ + 8)                        // padded row (shorts): breaks pow2 bank stride
#define GLD 33                               // Gram leading dim (fp32)

typedef short short8 __attribute__((ext_vector_type(8)));
typedef float f32x4  __attribute__((ext_vector_type(4)));

__device__ __forceinline__ unsigned f2bf2(float lo, float hi) {
  // round-to-nearest-even bf16 truncation, packed pair (lo in bits [15:0])
  unsigned ulo = __float_as_uint(lo);
  ulo += 0x7fffu + ((ulo >> 16) & 1u);
  unsigned uhi = __float_as_uint(hi);
  uhi += 0x7fffu + ((uhi >> 16) & 1u);
  return (uhi & 0xffff0000u) | (ulo >> 16);
}

__global__ __launch_bounds__(256) void phoneme_ssl_seg_kernel(
    const float* __restrict__ out,
    const int* __restrict__ batch_idx,
    const int* __restrict__ time_idx,
    const int* __restrict__ neg_idx,
    float* __restrict__ partials) {

  __shared__ __align__(16) unsigned short V[NF_ * RPAD];  // 20 x 520 bf16 = 20800 B
  __shared__ float G[32 * GLD];                           // 32x32 Gram, stride 33

  const int n = blockIdx.x;
  const int b = batch_idx[n];
  const int t = time_idx[n];
  const float* __restrict__ src = out + (size_t)(b * T_ + t) * NELEM;

  // ---- stage: fp32 global -> bf16 LDS, packed conversion, coalesced ----
  const float4* __restrict__ src4 = (const float4*)src;
#pragma unroll
  for (int it = 0; it < 5; ++it) {           // 1280 chunks of 8 floats / 256 threads
    const int c = threadIdx.x + 256 * it;
    const float4 x = src4[2 * c];
    const float4 y = src4[2 * c + 1];
    uint4 w;
    w.x = f2bf2(x.x, x.y);
    w.y = f2bf2(x.z, x.w);
    w.z = f2bf2(y.x, y.y);
    w.w = f2bf2(y.z, y.w);
    const int row = c >> 6;                  // 64 chunks (512 bf16) per row
    const int col = (c & 63) * 8;            // 16 B aligned (RPAD*2 = 1040 = 65*16)
    *(uint4*)&V[row * RPAD + col] = w;       // ds_write_b128
  }
  __syncthreads();

  // ---- Gram via MFMA, one 16x16 C-tile per wave: G = V * V^T ----
  {
    const int wave = threadIdx.x >> 6;       // 0:c00 1:c01 2:c10 3:c11
    const int lane = threadIdx.x & 63;
    const int r = lane & 15;
    const int q = lane >> 4;                 // quad: k = q*8 + j
    const int rowA = (wave >= 2) ? ((16 + r > 19) ? 19 : 16 + r) : r;   // A rows
    const int rowB = (wave & 1)  ? ((16 + r > 19) ? 19 : 16 + r) : r;   // B cols
    const unsigned short* pA = &V[rowA * RPAD + q * 8];
    const unsigned short* pB = &V[rowB * RPAD + q * 8];
    f32x4 acc = {0.f, 0.f, 0.f, 0.f};
#pragma unroll
    for (int ks = 0; ks < D_ / 32; ++ks) {   // 16 K-steps of 32
      const short8 a = *(const short8*)(pA + 32 * ks);   // ds_read_b128
      const short8 bb = (wave == 0 || wave == 3)
                          ? a                             // diagonal tiles: B == A
                          : *(const short8*)(pB + 32 * ks);
      // B fragment == A-layout fragment for Gram (B[k][n] = V[n][k])
      acc = __builtin_amdgcn_mfma_f32_16x16x32_bf16(a, bb, acc, 0, 0, 0);
    }
    // C/D layout (verified): col = lane&15, row = (lane>>4)*4 + reg
    const int rbase = (wave >= 2) ? 16 : 0;
    const int cbase = (wave & 1) ? 16 : 0;
#pragma unroll
    for (int reg = 0; reg < 4; ++reg)
      G[(rbase + q * 4 + reg) * GLD + cbase + r] = acc[reg];
  }
  __syncthreads();
  if (threadIdx.x >= 64) return;             // waves 1-3 done

  // ---- softmax rows from Gram, lanes 0..18 ----
  float local = 0.f;
  if (threadIdx.x < NPOS) {
    const int i = threadIdx.x;
    const float na = sqrtf(G[i * GLD + i]);
    float sims[1 + S_];
    {
      const float nb = sqrtf(G[(i + 1) * GLD + (i + 1)]);
      sims[0] = G[i * GLD + (i + 1)] / fmaxf(na * nb, EPS_);
    }
#pragma unroll
    for (int j = 0; j < S_; ++j) {
      const int f = neg_idx[i * S_ + j];
      const float nb = sqrtf(G[f * GLD + f]);
      sims[1 + j] = G[i * GLD + f] / fmaxf(na * nb, EPS_);
    }
    float m = sims[0];
#pragma unroll
    for (int j = 1; j < 1 + S_; ++j) m = fmaxf(m, sims[j]);
    float se = 0.f;
#pragma unroll
    for (int j = 0; j < 1 + S_; ++j) se += __expf(sims[j] - m);
    const float lse = m + __logf(se);
    local = -(sims[0] - lse);                // -log_softmax[...,0]
  }

  // ---- wave-0 reduce + plain per-block store ----
#pragma unroll
  for (int off = 32; off >= 1; off >>= 1)
    local += __shfl_xor(local, off, 64);
  if (threadIdx.x == 0)
    partials[n] = local;
}

__global__ __launch_bounds__(256) void phoneme_ssl_reduce_kernel(
    const float* __restrict__ partials, float* __restrict__ loss_out) {
  float acc = 0.f;
  for (int i = threadIdx.x; i < NSEG; i += 256) acc += partials[i];
#pragma unroll
  for (int off = 32; off >= 1; off >>= 1)
    acc += __shfl_xor(acc, off, 64);
  __shared__ float ws[4];
  if ((threadIdx.x & 63) == 0) ws[threadIdx.x >> 6] = acc;
  __syncthreads();
  if (threadIdx.x == 0)
    loss_out[0] = (ws[0] + ws[1] + ws[2] + ws[3]) * (1.0f / (float)(NSEG * NPOS));
}

extern "C" void kernel_launch(void* const* d_in, const int* in_sizes, int n_in,
                              void* d_out, int out_size, void* d_ws, size_t ws_size,
                              hipStream_t stream) {
  const float* out_t    = (const float*)d_in[0];
  const int* batch_idx  = (const int*)d_in[1];
  const int* time_idx   = (const int*)d_in[2];
  const int* neg_idx    = (const int*)d_in[3];
  float* loss_out       = (float*)d_out;
  float* partials       = (float*)d_ws;      // NSEG floats, fully overwritten each call

  phoneme_ssl_seg_kernel<<<NSEG, 256, 0, stream>>>(
      out_t, batch_idx, time_idx, neg_idx, partials);
  phoneme_ssl_reduce_kernel<<<1, 256, 0, stream>>>(partials, loss_out);
}